// Round 18
// baseline (316.814 us; speedup 1.0000x reference)
//
#include <hip/hip_runtime.h>
#include <hip/hip_bf16.h>
#include <hip/hip_fp16.h>

#define HCONC 128   // H*C
#define NHEAD 4
#define CCH   32
#define EDIM  8
#define NREL  16
#define BCAP  5120  // per-bucket capacity (mean ~4081, +16 sigma headroom)
#define TILE  2048  // edges per binA block

typedef float floatx2 __attribute__((ext_vector_type(2)));
typedef short bf16x8 __attribute__((ext_vector_type(8)));
typedef float f32x4 __attribute__((ext_vector_type(4)));

__device__ inline unsigned short pack_fp8x2(float a, float b) {
    return (unsigned short)(__builtin_amdgcn_cvt_pk_fp8_f32(a, b, 0, false) & 0xFFFF);
}
__device__ inline unsigned pack_bf2(float lo, float hi) {
    __hip_bfloat162 v;
    v.x = __float2bfloat16(lo);
    v.y = __float2bfloat16(hi);
    return *(unsigned*)&v;
}

// ---------------------------------------------------------------------------
// Merged init + weight-pack kernel.
// Blocks 0-63: W_l1/W_l2 -> MFMA B-frag (8 col-tiles).  Blocks 64-91: mlp W1
// -> MFMA B-frag (7 col-tiles, cols>=100 zero).  Block 92: cursors.
__global__ void initpack_kernel(const float* __restrict__ W_l1, const float* __restrict__ W_l2,
                                const float* __restrict__ mW1,
                                unsigned* __restrict__ Wl1q, unsigned* __restrict__ Wl2q,
                                unsigned* __restrict__ W1q,
                                int* __restrict__ gcursor, int* __restrict__ cnt, int nbuk) {
    if (blockIdx.x == 92) {
        int t = threadIdx.x;
        if (t < nbuk) gcursor[t] = t * BCAP;
        if (t < NREL) cnt[t] = 0;
        return;
    }
    int i = blockIdx.x * 256 + threadIdx.x;
    if (i < 16384) {                       // MFMA B-pack (W_l1 then W_l2)
        const float* W = (i < 8192) ? W_l1 : W_l2;
        unsigned* dst = (i < 8192) ? Wl1q : Wl2q;
        int r = i & 8191;
        int j2 = r & 3, lane = (r >> 2) & 63, kb = (r >> 8) & 3, t = r >> 10;
        int k0 = kb * 32 + ((lane >> 4) & 3) * 8 + 2 * j2;
        int c = 16 * t + (lane & 15);
        dst[r] = pack_bf2(W[k0 * 128 + c], W[(k0 + 1) * 128 + c]);
    } else if (i < 16384 + 7168) {         // mlp W1 B-pack, 7 tiles
        int r = i - 16384;
        int j2 = r & 3, lane = (r >> 2) & 63, kb = (r >> 8) & 3, t = r >> 10;
        int k0 = kb * 32 + ((lane >> 4) & 3) * 8 + 2 * j2;
        int c = 16 * t + (lane & 15);
        float lo = (c < 100) ? mW1[k0 * 100 + c] : 0.f;
        float hi = (c < 100) ? mW1[(k0 + 1) * 100 + c] : 0.f;
        W1q[r] = pack_bf2(lo, hi);
    }
}

// ---------------------------------------------------------------------------
// binA: tile-local counting sort by dst-bucket, coalesced run writes.
__global__ __launch_bounds__(256) void binA_kernel(
    const int* __restrict__ ei, const int* __restrict__ etype, int E, int nbuk,
    int* __restrict__ gcursor, int* __restrict__ cnt, uint2* __restrict__ ebuf) {
    __shared__ int hist[256], lbase[256], gbase[256], tmp[256];
    __shared__ int lcnt16[NREL];
    __shared__ uint2 srt[TILE];
    int t = threadIdx.x;
    hist[t] = 0;
    if (t < NREL) lcnt16[t] = 0;
    __syncthreads();

    int base = blockIdx.x * TILE;
    int count = min(TILE, E - base);

    uint2 rec[8]; int slot[8]; int buk[8];
#pragma unroll
    for (int i = 0; i < 8; i++) {
        int idx = t + i * 256;
        if (idx < count) {
            int g = base + idx;
            int s = ei[g], d = ei[E + g], ty = etype[g];
            rec[i].x = (unsigned)s | ((unsigned)ty << 16);
            rec[i].y = (unsigned)d;
            buk[i] = d >> 8;
            slot[i] = atomicAdd(&hist[buk[i]], 1);
            atomicAdd(&lcnt16[ty], 1);
        } else buk[i] = -1;
    }
    __syncthreads();

    int v = hist[t];
    tmp[t] = v; __syncthreads();
    for (int off = 1; off < 256; off <<= 1) {
        int add = (t >= off) ? tmp[t - off] : 0; __syncthreads();
        tmp[t] += add; __syncthreads();
    }
    lbase[t] = tmp[t] - v;
    if (t < nbuk && v > 0) gbase[t] = atomicAdd(&gcursor[t], v);  // reserve run
    __syncthreads();

#pragma unroll
    for (int i = 0; i < 8; i++)
        if (buk[i] >= 0) srt[lbase[buk[i]] + slot[i]] = rec[i];
    if (t < NREL) atomicAdd(&cnt[t], lcnt16[t]);
    __syncthreads();

    for (int idx = t; idx < count; idx += 256) {
        uint2 r = srt[idx];
        int b = (int)(r.y >> 8);
        int gpos = gbase[b] + idx - lbase[b];
        if (gpos < (b + 1) * BCAP) ebuf[gpos] = r;   // cap guard (never trips)
    }
}

// ---------------------------------------------------------------------------
// binB: per-bucket fine sort with inline bucket-base scan.  Block nbuk runs
// the (formerly separate) setup computation — one fewer launch.
__global__ __launch_bounds__(256) void binB_kernel(
    const uint2* __restrict__ ebuf, const int* __restrict__ gcursor, int n, int nbuk,
    int* __restrict__ row_ptr, unsigned* __restrict__ col,
    const float* __restrict__ W_l0, const float* __restrict__ emb,
    const int* __restrict__ cnt,
    const float* __restrict__ att_src, const float* __restrict__ att_dst,
    const float* __restrict__ att_edge, const float* __restrict__ W_edge,
    float* __restrict__ W0s, float* __restrict__ SA0, float* __restrict__ SD0,
    float* __restrict__ meanat, float* __restrict__ stab, int E) {
    __shared__ int hist[256], lcur[256], tmp[256];
    __shared__ unsigned colsl[BCAP];   // 20 KB
    int b = blockIdx.x, t = threadIdx.x;

    if (b == nbuk) {                   // fused setup block
        if (t < HCONC) {
            float s = 0.f;
            for (int k = 0; k < CCH; k++) s += W_l0[k * HCONC + t];
            W0s[t] = s;
        }
        __syncthreads();
        if (t < EDIM) {
            float s = 0.f;
            for (int r = 0; r < NREL; r++) s += (float)cnt[r] * emb[r * EDIM + t];
            meanat[t] = s / (float)E;
        }
        __syncthreads();
        if (t < NHEAD) {
            float sa = 0.f, sd = 0.f;
            for (int c = 0; c < CCH; c++) {
                sa += W0s[t * CCH + c] * att_src[t * CCH + c];
                sd += W0s[t * CCH + c] * att_dst[t * CCH + c];
            }
            SA0[t] = sa; SD0[t] = sd;
        }
        if (t < 3 * 68) {  // 3 layers x 17 types x 4 heads
            int l = t / 68, rem = t % 68, typ = rem >> 2, hh = rem & 3;
            const float* attr = (typ < NREL) ? &emb[typ * EDIM] : meanat;
            const float* We = W_edge + l * EDIM * HCONC;
            const float* ae = att_edge + l * HCONC + hh * CCH;
            float s = 0.f;
            for (int c = 0; c < CCH; c++) {
                float ev = 0.f;
                for (int d = 0; d < EDIM; d++) ev += attr[d] * We[d * HCONC + hh * CCH + c];
                s += ev * ae[c];
            }
            stab[t] = s;
        }
        return;
    }

    int c = (t < nbuk) ? (gcursor[t] - t * BCAP) : 0;
    tmp[t] = c; __syncthreads();
    for (int off = 1; off < 256; off <<= 1) {
        int add = (t >= off) ? tmp[t - off] : 0; __syncthreads();
        tmp[t] += add; __syncthreads();
    }
    int gstart = (b == 0) ? 0 : tmp[b - 1];
    if (b == 0 && t == nbuk - 1) row_ptr[n] = tmp[t];   // total edge count
    __syncthreads();

    int base = b * BCAP;
    int cntb = min(gcursor[b] - base, BCAP);
    hist[t] = 0;
    __syncthreads();
    for (int i = t; i < cntb; i += 256) {
        uint2 r = ebuf[base + i];
        atomicAdd(&hist[r.y & 255], 1);
    }
    __syncthreads();
    int v = hist[t];
    tmp[t] = v; __syncthreads();
    for (int off = 1; off < 256; off <<= 1) {
        int add = (t >= off) ? tmp[t - off] : 0; __syncthreads();
        tmp[t] += add; __syncthreads();
    }
    lcur[t] = tmp[t] - v;
    int gdst = (b << 8) + t;
    if (gdst < n) row_ptr[gdst] = gstart + tmp[t] - v;
    __syncthreads();
    for (int i = t; i < cntb; i += 256) {
        uint2 r = ebuf[base + i];
        int pos = atomicAdd(&lcur[r.y & 255], 1);
        colsl[pos] = r.x;
    }
    __syncthreads();
    for (int i = t; i < cntb; i += 256)
        col[gstart + i] = colsl[i];
}

// ---------------------------------------------------------------------------
// Layer-0 fused aggregation (h0 rank-1 -> per-(dst,head) scalar reduction).
__global__ __launch_bounds__(256) void agg0_kernel(
    const float* __restrict__ x, const int* __restrict__ row_ptr,
    const unsigned* __restrict__ col, const float* __restrict__ W0s,
    const float* __restrict__ SA0, const float* __restrict__ SD0,
    const float* __restrict__ tab, const float* __restrict__ bias,
    float* __restrict__ x_out, int n) {
    __shared__ float stab_s[68];
    if (threadIdx.x < 68) stab_s[threadIdx.x] = tab[threadIdx.x];
    __syncthreads();

    int tid = blockIdx.x * 256 + threadIdx.x;
    int d = tid >> 2, hh = tid & 3;
    if (d >= n) return;

    float xd = x[d];
    float sa = SA0[hh];
    float sdh = xd * SD0[hh];

    // self edge (typ=16, mean attr)
    float s = fmaf(xd, sa, sdh) + stab_s[64 + hh];
    s = s > 0.f ? s : 0.2f * s;
    float w = __expf(s);
    float den = w, sx = w * xd;

    int start = row_ptr[d], end = row_ptr[d + 1];
    for (int e = start; e < end; e++) {
        unsigned p = col[e];
        float xv = x[p & 0xFFFFu];
        int typ = (int)(p >> 16);
        float ss = fmaf(xv, sa, sdh) + stab_s[typ * 4 + hh];
        ss = ss > 0.f ? ss : 0.2f * ss;
        float ww = __expf(ss);
        den += ww;
        sx = fmaf(ww, xv, sx);
    }

    float val = sx / (den + 1e-16f);
    const float4* W4 = (const float4*)(W0s + hh * 32);
    const float4* b4 = (const float4*)(bias + hh * 32);
    float4* o4 = (float4*)(x_out + (size_t)d * HCONC + hh * 32);
#pragma unroll
    for (int j = 0; j < 8; j++) {
        float4 wv = W4[j], bv = b4[j];
        float4 ov;
        ov.x = fmaxf(fmaf(val, wv.x, bv.x), 0.f);
        ov.y = fmaxf(fmaf(val, wv.y, bv.y), 0.f);
        ov.z = fmaxf(fmaf(val, wv.z, bv.z), 0.f);
        ov.w = fmaxf(fmaf(val, wv.w, bv.w), 0.f);
        o4[j] = ov;
    }
}

// ---------------------------------------------------------------------------
// Dense transform via MFMA (v_mfma_f32_16x16x32_bf16), 16-row strip per wave.
__global__ __launch_bounds__(256, 2) void transform_kernel(
    const float* __restrict__ X, const unsigned* __restrict__ Wq,
    const float* __restrict__ a_src, const float* __restrict__ a_dst,
    unsigned short* __restrict__ h8, float* __restrict__ s_src,
    float* __restrict__ s_dst, int n) {
    __shared__ unsigned short hs[64 * 128];   // 16 KB epilogue transpose
    int tid = threadIdx.x;
    int lane = tid & 63;
    int wv = tid >> 6;
    int q = lane >> 4, nl = lane & 15;
    int row_blk = blockIdx.x * 64;
    int wrow = wv * 16;

    int arow = row_blk + wrow + nl;
    if (arow >= n) arow = n - 1;              // clamp; stores are guarded
    const float4* Xr = (const float4*)(X + (size_t)arow * HCONC);

    f32x4 acc[8];
#pragma unroll
    for (int t = 0; t < 8; t++) acc[t] = (f32x4){0.f, 0.f, 0.f, 0.f};

    const uint4* Wp4 = (const uint4*)Wq;
#pragma unroll
    for (int kb = 0; kb < 4; kb++) {
        float4 xa = Xr[kb * 8 + q * 2];
        float4 xb = Xr[kb * 8 + q * 2 + 1];
        uint4 ua;
        ua.x = pack_bf2(xa.x, xa.y);
        ua.y = pack_bf2(xa.z, xa.w);
        ua.z = pack_bf2(xb.x, xb.y);
        ua.w = pack_bf2(xb.z, xb.w);
        bf16x8 af = __builtin_bit_cast(bf16x8, ua);
#pragma unroll
        for (int t = 0; t < 8; t++) {
            uint4 ub = Wp4[(t * 4 + kb) * 64 + lane];
            bf16x8 bf = __builtin_bit_cast(bf16x8, ub);
            acc[t] = __builtin_amdgcn_mfma_f32_16x16x32_bf16(af, bf, acc[t], 0, 0, 0);
        }
    }

    // scores: lane holds col c=16t+nl of rows wrow+q*4+reg
    float av[8], dv[8];
#pragma unroll
    for (int t = 0; t < 8; t++) {
        av[t] = a_src[16 * t + nl];
        dv[t] = a_dst[16 * t + nl];
    }
#pragma unroll
    for (int reg = 0; reg < 4; reg++) {
        float t0 = acc[0][reg] * av[0] + acc[1][reg] * av[1];
        float t1 = acc[2][reg] * av[2] + acc[3][reg] * av[3];
        float t2 = acc[4][reg] * av[4] + acc[5][reg] * av[5];
        float t3 = acc[6][reg] * av[6] + acc[7][reg] * av[7];
        float d0 = acc[0][reg] * dv[0] + acc[1][reg] * dv[1];
        float d1 = acc[2][reg] * dv[2] + acc[3][reg] * dv[3];
        float d2 = acc[4][reg] * dv[4] + acc[5][reg] * dv[5];
        float d3 = acc[6][reg] * dv[6] + acc[7][reg] * dv[7];
#pragma unroll
        for (int off = 1; off <= 8; off <<= 1) {
            t0 += __shfl_xor(t0, off); t1 += __shfl_xor(t1, off);
            t2 += __shfl_xor(t2, off); t3 += __shfl_xor(t3, off);
            d0 += __shfl_xor(d0, off); d1 += __shfl_xor(d1, off);
            d2 += __shfl_xor(d2, off); d3 += __shfl_xor(d3, off);
        }
        int row = row_blk + wrow + q * 4 + reg;
        if (row < n && nl < 4) {
            float ts = nl == 0 ? t0 : nl == 1 ? t1 : nl == 2 ? t2 : t3;
            float td = nl == 0 ? d0 : nl == 1 ? d1 : nl == 2 ? d2 : d3;
            s_src[row * 4 + nl] = ts;
            s_dst[row * 4 + nl] = td;
        }
    }

    // h8: transpose acc through LDS (bf16) then pack fp8 coalesced
#pragma unroll
    for (int t = 0; t < 8; t++) {
#pragma unroll
        for (int reg = 0; reg < 4; reg++) {
            __hip_bfloat16 b = __float2bfloat16(acc[t][reg]);
            hs[(wrow + q * 4 + reg) * 128 + 16 * t + nl] = *(unsigned short*)&b;
        }
    }
    __syncthreads();
    const unsigned* hsu = (const unsigned*)hs;
#pragma unroll
    for (int i = 0; i < 16; i++) {
        int pidx = tid + i * 256;             // channel-pair index in 64x64
        int rl = pidx >> 6, cp = pidx & 63;
        int row = row_blk + rl;
        if (row < n) {
            unsigned u = hsu[rl * 64 + cp];
            float f0 = __uint_as_float(u << 16);
            float f1 = __uint_as_float(u & 0xFFFF0000u);
            h8[(size_t)row * 64 + cp] = pack_fp8x2(f0, f1);
        }
    }
}

// ---------------------------------------------------------------------------
// Softmax-aggregation v3: HEAD-PAIR passes.  Pass hpair touches only channels
// 64*hpair..+63 — one 64 B line per row, working set 3.2 MB < 4 MB per-XCD L2,
// so gathers go from LLC-bound to L2-resident.  Chunked score phase (lane
// computes one edge's 2 head-weights) + shuffle-broadcast inner loop.
// 4 streams x 16 lanes; lane owns 4 fp8 channels; self-loop analytic.
__global__ __launch_bounds__(256) void agg_kernel(
    const unsigned char* __restrict__ h8,   // fp8 e4m3, [n][128]
    const float* __restrict__ s_src, const float* __restrict__ s_dst,
    const int* __restrict__ row_ptr, const unsigned* __restrict__ col,
    const float* __restrict__ tab, const float* __restrict__ bias,
    const float* __restrict__ x_prev, float* __restrict__ x_out, int n, int hpair) {
    __shared__ __align__(16) float stab_s[68];
    if (threadIdx.x < 68) stab_s[threadIdx.x] = tab[threadIdx.x];
    __syncthreads();

    int d = __builtin_amdgcn_readfirstlane(blockIdx.x * 4 + (threadIdx.x >> 6));
    if (d >= n) return;
    int lane = threadIdx.x & 63;
    int strm = lane >> 4;             // 0..3
    int l16 = lane & 15;              // channel group: ch 64*hpair + 4*l16 ..+3
    int hloc = l16 >> 3;              // head within pair
    int head = 2 * hpair + hloc;

    int start = row_ptr[d], end = row_ptr[d + 1];
    float2 sd2 = ((const float2*)s_dst)[d * 2 + hpair];
    float sdh = hloc ? sd2.y : sd2.x;

    float den = 0.f;
    float a0 = 0.f, a1 = 0.f, a2 = 0.f, a3 = 0.f;

    if (strm == 0) {                  // self edge (typ=16, mean attr)
        float s = s_src[d * 4 + head] + sdh + stab_s[64 + head];
        s = s > 0.f ? s : 0.2f * s;
        float w = __expf(s);
        unsigned u = *(const unsigned*)(h8 + (size_t)d * 128 + hpair * 64 + 4 * l16);
        floatx2 f01 = __builtin_amdgcn_cvt_pk_f32_fp8((int)u, false);
        floatx2 f23 = __builtin_amdgcn_cvt_pk_f32_fp8((int)u, true);
        den = w;
        a0 = w * f01.x;  a1 = w * f01.y;
        a2 = w * f23.x;  a3 = w * f23.y;
    }

    for (int base = start; base < end; base += 64) {
        // score phase: lane computes edge base+lane's 2 head-weights
        float2 w2 = make_float2(0.f, 0.f);
        int esrc = 0;
        int e = base + lane;
        if (e < end) {
            unsigned pp = col[e];
            esrc = (int)(pp & 0xFFFFu);
            int typ = (int)(pp >> 16);
            float2 ss2 = ((const float2*)s_src)[esrc * 2 + hpair];
            float s0 = ss2.x + sd2.x + stab_s[typ * 4 + 2 * hpair];
            float s1 = ss2.y + sd2.y + stab_s[typ * 4 + 2 * hpair + 1];
            s0 = s0 > 0.f ? s0 : 0.2f * s0;
            s1 = s1 > 0.f ? s1 : 0.2f * s1;
            w2.x = __expf(s0); w2.y = __expf(s1);
        }
        int C = min(64, end - base);
        int steps = (C + 3) >> 2;
        for (int i = 0; i < steps; i++) {
            int j = i * 4 + strm;             // padding lanes carry w2 = 0
            float wx = __shfl(w2.x, j);
            float wy = __shfl(w2.y, j);
            int sj = __shfl(esrc, j);
            float w = hloc ? wy : wx;
            unsigned u = *(const unsigned*)(h8 + (size_t)sj * 128 + hpair * 64 + 4 * l16);
            floatx2 f01 = __builtin_amdgcn_cvt_pk_f32_fp8((int)u, false);
            floatx2 f23 = __builtin_amdgcn_cvt_pk_f32_fp8((int)u, true);
            den += w;
            a0 = fmaf(w, f01.x, a0);  a1 = fmaf(w, f01.y, a1);
            a2 = fmaf(w, f23.x, a2);  a3 = fmaf(w, f23.y, a3);
        }
    }

    // merge 4 streams: plain sums, xor16 then xor32
#pragma unroll
    for (int off = 16; off <= 32; off <<= 1) {
        den += __shfl_xor(den, off);
        a0 += __shfl_xor(a0, off);  a1 += __shfl_xor(a1, off);
        a2 += __shfl_xor(a2, off);  a3 += __shfl_xor(a3, off);
    }

    if (lane < 16) {
        float inv = 1.f / (den + 1e-16f);
        float4 bv = ((const float4*)bias)[hpair * 16 + l16];
        float4 ov;
        ov.x = a0 * inv + bv.x;
        ov.y = a1 * inv + bv.y;
        ov.z = a2 * inv + bv.z;
        ov.w = a3 * inv + bv.w;
        if (x_prev) {
            float4 pv = ((const float4*)x_prev)[(size_t)d * 32 + hpair * 16 + l16];
            ov.x += pv.x; ov.y += pv.y; ov.z += pv.z; ov.w += pv.w;
        }
        ov.x = fmaxf(ov.x, 0.f); ov.y = fmaxf(ov.y, 0.f);
        ov.z = fmaxf(ov.z, 0.f); ov.w = fmaxf(ov.w, 0.f);
        ((float4*)x_out)[(size_t)d * 32 + hpair * 16 + l16] = ov;
    }
}

// ---------------------------------------------------------------------------
// MLP head via MFMA: 7 col-tiles (hidden 0..111, >=100 zero-padded in pack).
__global__ __launch_bounds__(256, 2) void mlp_kernel(
    const float* __restrict__ X, const unsigned* __restrict__ W1q,
    const float* __restrict__ b1, const float* __restrict__ W2,
    const float* __restrict__ b2, float* __restrict__ out, int n) {
    int tid = threadIdx.x;
    int lane = tid & 63;
    int wv = tid >> 6;
    int q = lane >> 4, nl = lane & 15;
    int row_blk = blockIdx.x * 64;
    int wrow = wv * 16;

    int arow = row_blk + wrow + nl;
    if (arow >= n) arow = n - 1;
    const float4* Xr = (const float4*)(X + (size_t)arow * HCONC);

    f32x4 acc[7];
#pragma unroll
    for (int t = 0; t < 7; t++) acc[t] = (f32x4){0.f, 0.f, 0.f, 0.f};

    const uint4* Wp4 = (const uint4*)W1q;
#pragma unroll
    for (int kb = 0; kb < 4; kb++) {
        float4 xa = Xr[kb * 8 + q * 2];
        float4 xb = Xr[kb * 8 + q * 2 + 1];
        uint4 ua;
        ua.x = pack_bf2(xa.x, xa.y);
        ua.y = pack_bf2(xa.z, xa.w);
        ua.z = pack_bf2(xb.x, xb.y);
        ua.w = pack_bf2(xb.z, xb.w);
        bf16x8 af = __builtin_bit_cast(bf16x8, ua);
#pragma unroll
        for (int t = 0; t < 7; t++) {
            uint4 ub = Wp4[(t * 4 + kb) * 64 + lane];
            bf16x8 bf = __builtin_bit_cast(bf16x8, ub);
            acc[t] = __builtin_amdgcn_mfma_f32_16x16x32_bf16(af, bf, acc[t], 0, 0, 0);
        }
    }

    float b1c[7], w2c[7];
#pragma unroll
    for (int t = 0; t < 7; t++) {
        int c = 16 * t + nl;
        bool vld = c < 100;
        b1c[t] = vld ? b1[c] : 0.f;
        w2c[t] = vld ? W2[c] : 0.f;
    }
    float b2v = b2[0];

#pragma unroll
    for (int reg = 0; reg < 4; reg++) {
        float sum = 0.f;
#pragma unroll
        for (int t = 0; t < 7; t++) {
            float hv = fmaxf(acc[t][reg] + b1c[t], 0.f);
            sum = fmaf(hv, w2c[t], sum);
        }
#pragma unroll
        for (int off = 1; off <= 8; off <<= 1)
            sum += __shfl_xor(sum, off);
        int row = row_blk + wrow + q * 4 + reg;
        if (nl == 0 && row < n)
            out[row] = 1.f / (1.f + __expf(-(sum + b2v)));
    }
}

// ---------------------------------------------------------------------------
extern "C" void kernel_launch(void* const* d_in, const int* in_sizes, int n_in,
                              void* d_out, int out_size, void* d_ws, size_t ws_size,
                              hipStream_t stream) {
    const float* x       = (const float*)d_in[0];
    const int*   ei      = (const int*)d_in[1];     // [2,E]: src then dst
    const int*   etype   = (const int*)d_in[2];
    const float* emb     = (const float*)d_in[3];   // [16,8]
    const float* W_l0    = (const float*)d_in[4];   // [32,128]
    const float* W_l1    = (const float*)d_in[5];   // [128,128]
    const float* W_l2    = (const float*)d_in[6];   // [128,128]
    const float* att_src = (const float*)d_in[7];   // [3,4,32]
    const float* att_dst = (const float*)d_in[8];
    const float* att_edge= (const float*)d_in[9];
    const float* W_edge  = (const float*)d_in[10];  // [3,8,128]
    const float* bias    = (const float*)d_in[11];  // [3,128]
    const float* mW1     = (const float*)d_in[12];  // [128,100]
    const float* mb1     = (const float*)d_in[13];
    const float* mW2     = (const float*)d_in[14];  // [100,1]
    const float* mb2     = (const float*)d_in[15];

    int n = in_sizes[0];   // 50000
    int E = in_sizes[2];   // 800000
    int nbuk = (n + 255) >> 8;   // 196

    // workspace carve (keep 16-byte alignment for uint4 views)
    float* p   = (float*)d_ws;
    float* xa  = p; p += (size_t)n * HCONC;
    float* xb  = p; p += (size_t)n * HCONC;
    float* ssrc = p; p += (size_t)n * NHEAD;
    float* sdst = p; p += (size_t)n * NHEAD;
    float* hbf  = p; p += (size_t)n * 32;          // fp8 h buffer (n*128 bytes)
    unsigned* Wl1q = (unsigned*)p; p += 8192;      // MFMA-B-packed W_l1
    unsigned* Wl2q = (unsigned*)p; p += 8192;      // MFMA-B-packed W_l2
    unsigned* W1q  = (unsigned*)p; p += 7168;      // MFMA-B-packed mW1 (7 tiles)
    int* row_ptr     = (int*)p;
    int* gcursor     = row_ptr + n + 1;
    int* cnt         = gcursor + 256;
    float* W0s    = (float*)(cnt + 16);
    float* SA0    = W0s + HCONC;
    float* SD0    = SA0 + NHEAD;
    float* meanat = SD0 + NHEAD;
    float* stab   = meanat + EDIM;   // 3*68 = 204, round to 256
    char* raw = (char*)(stab + 256);
    uint2* ebuf = (uint2*)(((uintptr_t)raw + 15) & ~(uintptr_t)15);  // nbuk*BCAP
    unsigned* col = (unsigned*)(ebuf + (size_t)nbuk * BCAP);         // E entries

    // CSR build: initpack -> tile counting-sort (binA) -> fine sort + setup (binB)
    initpack_kernel<<<93, 256, 0, stream>>>(W_l1, W_l2, mW1, Wl1q, Wl2q, W1q,
                                            gcursor, cnt, nbuk);
    binA_kernel<<<(E + TILE - 1) / TILE, 256, 0, stream>>>(ei, etype, E, nbuk,
                                                           gcursor, cnt, ebuf);
    binB_kernel<<<nbuk + 1, 256, 0, stream>>>(ebuf, gcursor, n, nbuk, row_ptr, col,
                                              W_l0, emb, cnt, att_src, att_dst,
                                              att_edge, W_edge, W0s, SA0, SD0,
                                              meanat, stab, E);

    // layer 0: fully-fused rank-1 aggregation (no h materialization)
    agg0_kernel<<<(n * 4 + 255) / 256, 256, 0, stream>>>(x, row_ptr, col, W0s, SA0, SD0,
                                                         stab + 0, bias + 0, xa, n);
    // layer 1
    transform_kernel<<<(n + 63) / 64, 256, 0, stream>>>(xa, Wl1q, att_src + 128, att_dst + 128,
                                                        (unsigned short*)hbf, ssrc, sdst, n);
    agg_kernel<<<(n + 3) / 4, 256, 0, stream>>>((const unsigned char*)hbf, ssrc, sdst, row_ptr, col,
                                                stab + 68, bias + 128, xa, xb, n, 0);
    agg_kernel<<<(n + 3) / 4, 256, 0, stream>>>((const unsigned char*)hbf, ssrc, sdst, row_ptr, col,
                                                stab + 68, bias + 128, xa, xb, n, 1);
    // layer 2
    transform_kernel<<<(n + 63) / 64, 256, 0, stream>>>(xb, Wl2q, att_src + 256, att_dst + 256,
                                                        (unsigned short*)hbf, ssrc, sdst, n);
    agg_kernel<<<(n + 3) / 4, 256, 0, stream>>>((const unsigned char*)hbf, ssrc, sdst, row_ptr, col,
                                                stab + 136, bias + 256, xb, xa, n, 0);
    agg_kernel<<<(n + 3) / 4, 256, 0, stream>>>((const unsigned char*)hbf, ssrc, sdst, row_ptr, col,
                                                stab + 136, bias + 256, xb, xa, n, 1);
    // MLP head (MFMA)
    mlp_kernel<<<(n + 63) / 64, 256, 0, stream>>>(xa, W1q, mb1, mW2, mb2, (float*)d_out, n);
}

// Round 19
// 261.983 us; speedup vs baseline: 1.2093x; 1.2093x over previous
//
#include <hip/hip_runtime.h>
#include <hip/hip_bf16.h>
#include <hip/hip_fp16.h>

#define HCONC 128   // H*C
#define NHEAD 4
#define CCH   32
#define EDIM  8
#define NREL  16
#define BCAP  5120  // per-bucket capacity (mean ~4081, +16 sigma headroom)
#define TILE  2048  // edges per binA block

typedef float floatx2 __attribute__((ext_vector_type(2)));
typedef short bf16x8 __attribute__((ext_vector_type(8)));
typedef float f32x4 __attribute__((ext_vector_type(4)));

__device__ inline unsigned short pack_fp8x2(float a, float b) {
    return (unsigned short)(__builtin_amdgcn_cvt_pk_fp8_f32(a, b, 0, false) & 0xFFFF);
}
__device__ inline unsigned pack_bf2(float lo, float hi) {
    __hip_bfloat162 v;
    v.x = __float2bfloat16(lo);
    v.y = __float2bfloat16(hi);
    return *(unsigned*)&v;
}

// ---------------------------------------------------------------------------
// Merged init + weight-pack kernel.
// Blocks 0-63: W_l1/W_l2 -> MFMA B-frag (8 col-tiles).  Blocks 64-91: mlp W1
// -> MFMA B-frag (7 col-tiles, cols>=100 zero).  Block 92: cursors.
__global__ void initpack_kernel(const float* __restrict__ W_l1, const float* __restrict__ W_l2,
                                const float* __restrict__ mW1,
                                unsigned* __restrict__ Wl1q, unsigned* __restrict__ Wl2q,
                                unsigned* __restrict__ W1q,
                                int* __restrict__ gcursor, int* __restrict__ cnt, int nbuk) {
    if (blockIdx.x == 92) {
        int t = threadIdx.x;
        if (t < nbuk) gcursor[t] = t * BCAP;
        if (t < NREL) cnt[t] = 0;
        return;
    }
    int i = blockIdx.x * 256 + threadIdx.x;
    if (i < 16384) {                       // MFMA B-pack (W_l1 then W_l2)
        const float* W = (i < 8192) ? W_l1 : W_l2;
        unsigned* dst = (i < 8192) ? Wl1q : Wl2q;
        int r = i & 8191;
        int j2 = r & 3, lane = (r >> 2) & 63, kb = (r >> 8) & 3, t = r >> 10;
        int k0 = kb * 32 + ((lane >> 4) & 3) * 8 + 2 * j2;
        int c = 16 * t + (lane & 15);
        dst[r] = pack_bf2(W[k0 * 128 + c], W[(k0 + 1) * 128 + c]);
    } else if (i < 16384 + 7168) {         // mlp W1 B-pack, 7 tiles
        int r = i - 16384;
        int j2 = r & 3, lane = (r >> 2) & 63, kb = (r >> 8) & 3, t = r >> 10;
        int k0 = kb * 32 + ((lane >> 4) & 3) * 8 + 2 * j2;
        int c = 16 * t + (lane & 15);
        float lo = (c < 100) ? mW1[k0 * 100 + c] : 0.f;
        float hi = (c < 100) ? mW1[(k0 + 1) * 100 + c] : 0.f;
        W1q[r] = pack_bf2(lo, hi);
    }
}

// ---------------------------------------------------------------------------
// binA: tile-local counting sort by dst-bucket, coalesced run writes.
__global__ __launch_bounds__(256) void binA_kernel(
    const int* __restrict__ ei, const int* __restrict__ etype, int E, int nbuk,
    int* __restrict__ gcursor, int* __restrict__ cnt, uint2* __restrict__ ebuf) {
    __shared__ int hist[256], lbase[256], gbase[256], tmp[256];
    __shared__ int lcnt16[NREL];
    __shared__ uint2 srt[TILE];
    int t = threadIdx.x;
    hist[t] = 0;
    if (t < NREL) lcnt16[t] = 0;
    __syncthreads();

    int base = blockIdx.x * TILE;
    int count = min(TILE, E - base);

    uint2 rec[8]; int slot[8]; int buk[8];
#pragma unroll
    for (int i = 0; i < 8; i++) {
        int idx = t + i * 256;
        if (idx < count) {
            int g = base + idx;
            int s = ei[g], d = ei[E + g], ty = etype[g];
            rec[i].x = (unsigned)s | ((unsigned)ty << 16);
            rec[i].y = (unsigned)d;
            buk[i] = d >> 8;
            slot[i] = atomicAdd(&hist[buk[i]], 1);
            atomicAdd(&lcnt16[ty], 1);
        } else buk[i] = -1;
    }
    __syncthreads();

    int v = hist[t];
    tmp[t] = v; __syncthreads();
    for (int off = 1; off < 256; off <<= 1) {
        int add = (t >= off) ? tmp[t - off] : 0; __syncthreads();
        tmp[t] += add; __syncthreads();
    }
    lbase[t] = tmp[t] - v;
    if (t < nbuk && v > 0) gbase[t] = atomicAdd(&gcursor[t], v);  // reserve run
    __syncthreads();

#pragma unroll
    for (int i = 0; i < 8; i++)
        if (buk[i] >= 0) srt[lbase[buk[i]] + slot[i]] = rec[i];
    if (t < NREL) atomicAdd(&cnt[t], lcnt16[t]);
    __syncthreads();

    for (int idx = t; idx < count; idx += 256) {
        uint2 r = srt[idx];
        int b = (int)(r.y >> 8);
        int gpos = gbase[b] + idx - lbase[b];
        if (gpos < (b + 1) * BCAP) ebuf[gpos] = r;   // cap guard (never trips)
    }
}

// ---------------------------------------------------------------------------
// binB: per-bucket fine sort with inline bucket-base scan.  Block nbuk runs
// the (formerly separate) setup computation — one fewer launch.
__global__ __launch_bounds__(256) void binB_kernel(
    const uint2* __restrict__ ebuf, const int* __restrict__ gcursor, int n, int nbuk,
    int* __restrict__ row_ptr, unsigned* __restrict__ col,
    const float* __restrict__ W_l0, const float* __restrict__ emb,
    const int* __restrict__ cnt,
    const float* __restrict__ att_src, const float* __restrict__ att_dst,
    const float* __restrict__ att_edge, const float* __restrict__ W_edge,
    float* __restrict__ W0s, float* __restrict__ SA0, float* __restrict__ SD0,
    float* __restrict__ meanat, float* __restrict__ stab, int E) {
    __shared__ int hist[256], lcur[256], tmp[256];
    __shared__ unsigned colsl[BCAP];   // 20 KB
    int b = blockIdx.x, t = threadIdx.x;

    if (b == nbuk) {                   // fused setup block
        if (t < HCONC) {
            float s = 0.f;
            for (int k = 0; k < CCH; k++) s += W_l0[k * HCONC + t];
            W0s[t] = s;
        }
        __syncthreads();
        if (t < EDIM) {
            float s = 0.f;
            for (int r = 0; r < NREL; r++) s += (float)cnt[r] * emb[r * EDIM + t];
            meanat[t] = s / (float)E;
        }
        __syncthreads();
        if (t < NHEAD) {
            float sa = 0.f, sd = 0.f;
            for (int c = 0; c < CCH; c++) {
                sa += W0s[t * CCH + c] * att_src[t * CCH + c];
                sd += W0s[t * CCH + c] * att_dst[t * CCH + c];
            }
            SA0[t] = sa; SD0[t] = sd;
        }
        if (t < 3 * 68) {  // 3 layers x 17 types x 4 heads
            int l = t / 68, rem = t % 68, typ = rem >> 2, hh = rem & 3;
            const float* attr = (typ < NREL) ? &emb[typ * EDIM] : meanat;
            const float* We = W_edge + l * EDIM * HCONC;
            const float* ae = att_edge + l * HCONC + hh * CCH;
            float s = 0.f;
            for (int c = 0; c < CCH; c++) {
                float ev = 0.f;
                for (int d = 0; d < EDIM; d++) ev += attr[d] * We[d * HCONC + hh * CCH + c];
                s += ev * ae[c];
            }
            stab[t] = s;
        }
        return;
    }

    int c = (t < nbuk) ? (gcursor[t] - t * BCAP) : 0;
    tmp[t] = c; __syncthreads();
    for (int off = 1; off < 256; off <<= 1) {
        int add = (t >= off) ? tmp[t - off] : 0; __syncthreads();
        tmp[t] += add; __syncthreads();
    }
    int gstart = (b == 0) ? 0 : tmp[b - 1];
    if (b == 0 && t == nbuk - 1) row_ptr[n] = tmp[t];   // total edge count
    __syncthreads();

    int base = b * BCAP;
    int cntb = min(gcursor[b] - base, BCAP);
    hist[t] = 0;
    __syncthreads();
    for (int i = t; i < cntb; i += 256) {
        uint2 r = ebuf[base + i];
        atomicAdd(&hist[r.y & 255], 1);
    }
    __syncthreads();
    int v = hist[t];
    tmp[t] = v; __syncthreads();
    for (int off = 1; off < 256; off <<= 1) {
        int add = (t >= off) ? tmp[t - off] : 0; __syncthreads();
        tmp[t] += add; __syncthreads();
    }
    lcur[t] = tmp[t] - v;
    int gdst = (b << 8) + t;
    if (gdst < n) row_ptr[gdst] = gstart + tmp[t] - v;
    __syncthreads();
    for (int i = t; i < cntb; i += 256) {
        uint2 r = ebuf[base + i];
        int pos = atomicAdd(&lcur[r.y & 255], 1);
        colsl[pos] = r.x;
    }
    __syncthreads();
    for (int i = t; i < cntb; i += 256)
        col[gstart + i] = colsl[i];
}

// ---------------------------------------------------------------------------
// Layer-0 fused aggregation (h0 rank-1 -> per-(dst,head) scalar reduction).
__global__ __launch_bounds__(256) void agg0_kernel(
    const float* __restrict__ x, const int* __restrict__ row_ptr,
    const unsigned* __restrict__ col, const float* __restrict__ W0s,
    const float* __restrict__ SA0, const float* __restrict__ SD0,
    const float* __restrict__ tab, const float* __restrict__ bias,
    float* __restrict__ x_out, int n) {
    __shared__ float stab_s[68];
    if (threadIdx.x < 68) stab_s[threadIdx.x] = tab[threadIdx.x];
    __syncthreads();

    int tid = blockIdx.x * 256 + threadIdx.x;
    int d = tid >> 2, hh = tid & 3;
    if (d >= n) return;

    float xd = x[d];
    float sa = SA0[hh];
    float sdh = xd * SD0[hh];

    // self edge (typ=16, mean attr)
    float s = fmaf(xd, sa, sdh) + stab_s[64 + hh];
    s = s > 0.f ? s : 0.2f * s;
    float w = __expf(s);
    float den = w, sx = w * xd;

    int start = row_ptr[d], end = row_ptr[d + 1];
    for (int e = start; e < end; e++) {
        unsigned p = col[e];
        float xv = x[p & 0xFFFFu];
        int typ = (int)(p >> 16);
        float ss = fmaf(xv, sa, sdh) + stab_s[typ * 4 + hh];
        ss = ss > 0.f ? ss : 0.2f * ss;
        float ww = __expf(ss);
        den += ww;
        sx = fmaf(ww, xv, sx);
    }

    float val = sx / (den + 1e-16f);
    const float4* W4 = (const float4*)(W0s + hh * 32);
    const float4* b4 = (const float4*)(bias + hh * 32);
    float4* o4 = (float4*)(x_out + (size_t)d * HCONC + hh * 32);
#pragma unroll
    for (int j = 0; j < 8; j++) {
        float4 wv = W4[j], bv = b4[j];
        float4 ov;
        ov.x = fmaxf(fmaf(val, wv.x, bv.x), 0.f);
        ov.y = fmaxf(fmaf(val, wv.y, bv.y), 0.f);
        ov.z = fmaxf(fmaf(val, wv.z, bv.z), 0.f);
        ov.w = fmaxf(fmaf(val, wv.w, bv.w), 0.f);
        o4[j] = ov;
    }
}

// ---------------------------------------------------------------------------
// Dense transform via MFMA (v_mfma_f32_16x16x32_bf16), 16-row strip per wave.
__global__ __launch_bounds__(256, 2) void transform_kernel(
    const float* __restrict__ X, const unsigned* __restrict__ Wq,
    const float* __restrict__ a_src, const float* __restrict__ a_dst,
    unsigned short* __restrict__ h8, float* __restrict__ s_src,
    float* __restrict__ s_dst, int n) {
    __shared__ unsigned short hs[64 * 128];   // 16 KB epilogue transpose
    int tid = threadIdx.x;
    int lane = tid & 63;
    int wv = tid >> 6;
    int q = lane >> 4, nl = lane & 15;
    int row_blk = blockIdx.x * 64;
    int wrow = wv * 16;

    int arow = row_blk + wrow + nl;
    if (arow >= n) arow = n - 1;              // clamp; stores are guarded
    const float4* Xr = (const float4*)(X + (size_t)arow * HCONC);

    f32x4 acc[8];
#pragma unroll
    for (int t = 0; t < 8; t++) acc[t] = (f32x4){0.f, 0.f, 0.f, 0.f};

    const uint4* Wp4 = (const uint4*)Wq;
#pragma unroll
    for (int kb = 0; kb < 4; kb++) {
        float4 xa = Xr[kb * 8 + q * 2];
        float4 xb = Xr[kb * 8 + q * 2 + 1];
        uint4 ua;
        ua.x = pack_bf2(xa.x, xa.y);
        ua.y = pack_bf2(xa.z, xa.w);
        ua.z = pack_bf2(xb.x, xb.y);
        ua.w = pack_bf2(xb.z, xb.w);
        bf16x8 af = __builtin_bit_cast(bf16x8, ua);
#pragma unroll
        for (int t = 0; t < 8; t++) {
            uint4 ub = Wp4[(t * 4 + kb) * 64 + lane];
            bf16x8 bf = __builtin_bit_cast(bf16x8, ub);
            acc[t] = __builtin_amdgcn_mfma_f32_16x16x32_bf16(af, bf, acc[t], 0, 0, 0);
        }
    }

    // scores: lane holds col c=16t+nl of rows wrow+q*4+reg
    float av[8], dv[8];
#pragma unroll
    for (int t = 0; t < 8; t++) {
        av[t] = a_src[16 * t + nl];
        dv[t] = a_dst[16 * t + nl];
    }
#pragma unroll
    for (int reg = 0; reg < 4; reg++) {
        float t0 = acc[0][reg] * av[0] + acc[1][reg] * av[1];
        float t1 = acc[2][reg] * av[2] + acc[3][reg] * av[3];
        float t2 = acc[4][reg] * av[4] + acc[5][reg] * av[5];
        float t3 = acc[6][reg] * av[6] + acc[7][reg] * av[7];
        float d0 = acc[0][reg] * dv[0] + acc[1][reg] * dv[1];
        float d1 = acc[2][reg] * dv[2] + acc[3][reg] * dv[3];
        float d2 = acc[4][reg] * dv[4] + acc[5][reg] * dv[5];
        float d3 = acc[6][reg] * dv[6] + acc[7][reg] * dv[7];
#pragma unroll
        for (int off = 1; off <= 8; off <<= 1) {
            t0 += __shfl_xor(t0, off); t1 += __shfl_xor(t1, off);
            t2 += __shfl_xor(t2, off); t3 += __shfl_xor(t3, off);
            d0 += __shfl_xor(d0, off); d1 += __shfl_xor(d1, off);
            d2 += __shfl_xor(d2, off); d3 += __shfl_xor(d3, off);
        }
        int row = row_blk + wrow + q * 4 + reg;
        if (row < n && nl < 4) {
            float ts = nl == 0 ? t0 : nl == 1 ? t1 : nl == 2 ? t2 : t3;
            float td = nl == 0 ? d0 : nl == 1 ? d1 : nl == 2 ? d2 : d3;
            s_src[row * 4 + nl] = ts;
            s_dst[row * 4 + nl] = td;
        }
    }

    // h8: transpose acc through LDS (bf16) then pack fp8 coalesced
#pragma unroll
    for (int t = 0; t < 8; t++) {
#pragma unroll
        for (int reg = 0; reg < 4; reg++) {
            __hip_bfloat16 b = __float2bfloat16(acc[t][reg]);
            hs[(wrow + q * 4 + reg) * 128 + 16 * t + nl] = *(unsigned short*)&b;
        }
    }
    __syncthreads();
    const unsigned* hsu = (const unsigned*)hs;
#pragma unroll
    for (int i = 0; i < 16; i++) {
        int pidx = tid + i * 256;             // channel-pair index in 64x64
        int rl = pidx >> 6, cp = pidx & 63;
        int row = row_blk + rl;
        if (row < n) {
            unsigned u = hsu[rl * 64 + cp];
            float f0 = __uint_as_float(u << 16);
            float f1 = __uint_as_float(u & 0xFFFF0000u);
            h8[(size_t)row * 64 + cp] = pack_fp8x2(f0, f1);
        }
    }
}

// ---------------------------------------------------------------------------
// Softmax-aggregation v2: chunked score phase (each lane computes ONE edge's
// 4 head-weights — 4 exps/edge, one float4 s_src load/edge) +
// shuffle-broadcast inner loop (register exchange, no extra gathers).
// 4 streams x 16 lanes; lane owns 8 fp8 channels; self-loop analytic.
// (Round 18's head-pair split regressed 270->317: doubling score/col/merge
// outweighed any L2-residency gain — this v2 form is the measured optimum.)
__global__ __launch_bounds__(256) void agg_kernel(
    const unsigned char* __restrict__ h8,   // fp8 e4m3, [n][128]
    const float* __restrict__ s_src, const float* __restrict__ s_dst,
    const int* __restrict__ row_ptr, const unsigned* __restrict__ col,
    const float* __restrict__ tab, const float* __restrict__ bias,
    const float* __restrict__ x_prev, float* __restrict__ x_out, int n) {
    __shared__ __align__(16) float stab_s[68];
    if (threadIdx.x < 68) stab_s[threadIdx.x] = tab[threadIdx.x];
    __syncthreads();

    int d = __builtin_amdgcn_readfirstlane(blockIdx.x * 4 + (threadIdx.x >> 6));
    if (d >= n) return;
    int lane = threadIdx.x & 63;
    int strm = lane >> 4;             // 0..3
    int l16 = lane & 15;              // channel group within row
    int head = l16 >> 2;              // 4 lanes/head

    int start = row_ptr[d], end = row_ptr[d + 1];
    float4 sd4 = ((const float4*)s_dst)[d];

    float den = 0.f;
    float a0 = 0.f, a1 = 0.f, a2 = 0.f, a3 = 0.f;
    float a4 = 0.f, a5 = 0.f, a6 = 0.f, a7 = 0.f;

    if (strm == 0) {                  // self edge (typ=16, mean attr)
        float sdh = head == 0 ? sd4.x : head == 1 ? sd4.y : head == 2 ? sd4.z : sd4.w;
        float s = s_src[d * 4 + head] + sdh + stab_s[64 + head];
        s = s > 0.f ? s : 0.2f * s;
        float w = __expf(s);
        uint2 u = ((const uint2*)(h8 + (size_t)d * 128))[l16];
        floatx2 f01 = __builtin_amdgcn_cvt_pk_f32_fp8((int)u.x, false);
        floatx2 f23 = __builtin_amdgcn_cvt_pk_f32_fp8((int)u.x, true);
        floatx2 f45 = __builtin_amdgcn_cvt_pk_f32_fp8((int)u.y, false);
        floatx2 f67 = __builtin_amdgcn_cvt_pk_f32_fp8((int)u.y, true);
        den = w;
        a0 = w * f01.x;  a1 = w * f01.y;
        a2 = w * f23.x;  a3 = w * f23.y;
        a4 = w * f45.x;  a5 = w * f45.y;
        a6 = w * f67.x;  a7 = w * f67.y;
    }

    for (int base = start; base < end; base += 64) {
        // score phase: lane computes edge base+lane's 4 head-weights
        float4 w4 = make_float4(0.f, 0.f, 0.f, 0.f);
        int esrc = 0;
        int e = base + lane;
        if (e < end) {
            unsigned pp = col[e];
            esrc = (int)(pp & 0xFFFFu);
            int typ = (int)(pp >> 16);
            float4 ss4 = ((const float4*)s_src)[esrc];
            float4 st4 = *(const float4*)&stab_s[typ * 4];
            float s0 = ss4.x + sd4.x + st4.x;
            float s1 = ss4.y + sd4.y + st4.y;
            float s2 = ss4.z + sd4.z + st4.z;
            float s3 = ss4.w + sd4.w + st4.w;
            s0 = s0 > 0.f ? s0 : 0.2f * s0;
            s1 = s1 > 0.f ? s1 : 0.2f * s1;
            s2 = s2 > 0.f ? s2 : 0.2f * s2;
            s3 = s3 > 0.f ? s3 : 0.2f * s3;
            w4.x = __expf(s0); w4.y = __expf(s1);
            w4.z = __expf(s2); w4.w = __expf(s3);
        }
        int C = min(64, end - base);
        int steps = (C + 3) >> 2;
        for (int i = 0; i < steps; i++) {
            int j = i * 4 + strm;             // padding lanes carry w4 = 0
            float wx = __shfl(w4.x, j);
            float wy = __shfl(w4.y, j);
            float wz = __shfl(w4.z, j);
            float ww = __shfl(w4.w, j);
            int sj = __shfl(esrc, j);
            float w = head == 0 ? wx : head == 1 ? wy : head == 2 ? wz : ww;
            uint2 u = ((const uint2*)(h8 + (size_t)sj * 128))[l16];
            floatx2 f01 = __builtin_amdgcn_cvt_pk_f32_fp8((int)u.x, false);
            floatx2 f23 = __builtin_amdgcn_cvt_pk_f32_fp8((int)u.x, true);
            floatx2 f45 = __builtin_amdgcn_cvt_pk_f32_fp8((int)u.y, false);
            floatx2 f67 = __builtin_amdgcn_cvt_pk_f32_fp8((int)u.y, true);
            den += w;
            a0 = fmaf(w, f01.x, a0);  a1 = fmaf(w, f01.y, a1);
            a2 = fmaf(w, f23.x, a2);  a3 = fmaf(w, f23.y, a3);
            a4 = fmaf(w, f45.x, a4);  a5 = fmaf(w, f45.y, a5);
            a6 = fmaf(w, f67.x, a6);  a7 = fmaf(w, f67.y, a7);
        }
    }

    // merge 4 streams: plain sums, xor16 then xor32
#pragma unroll
    for (int off = 16; off <= 32; off <<= 1) {
        den += __shfl_xor(den, off);
        a0 += __shfl_xor(a0, off);  a1 += __shfl_xor(a1, off);
        a2 += __shfl_xor(a2, off);  a3 += __shfl_xor(a3, off);
        a4 += __shfl_xor(a4, off);  a5 += __shfl_xor(a5, off);
        a6 += __shfl_xor(a6, off);  a7 += __shfl_xor(a7, off);
    }

    if (lane < 16) {
        float inv = 1.f / (den + 1e-16f);
        float4 b0 = ((const float4*)bias)[2 * l16];
        float4 b1v = ((const float4*)bias)[2 * l16 + 1];
        float4 o0v, o1v;
        o0v.x = a0 * inv + b0.x;  o0v.y = a1 * inv + b0.y;
        o0v.z = a2 * inv + b0.z;  o0v.w = a3 * inv + b0.w;
        o1v.x = a4 * inv + b1v.x; o1v.y = a5 * inv + b1v.y;
        o1v.z = a6 * inv + b1v.z; o1v.w = a7 * inv + b1v.w;
        if (x_prev) {
            float4 p0 = ((const float4*)x_prev)[(size_t)d * 32 + 2 * l16];
            float4 p1 = ((const float4*)x_prev)[(size_t)d * 32 + 2 * l16 + 1];
            o0v.x += p0.x; o0v.y += p0.y; o0v.z += p0.z; o0v.w += p0.w;
            o1v.x += p1.x; o1v.y += p1.y; o1v.z += p1.z; o1v.w += p1.w;
        }
        o0v.x = fmaxf(o0v.x, 0.f); o0v.y = fmaxf(o0v.y, 0.f);
        o0v.z = fmaxf(o0v.z, 0.f); o0v.w = fmaxf(o0v.w, 0.f);
        o1v.x = fmaxf(o1v.x, 0.f); o1v.y = fmaxf(o1v.y, 0.f);
        o1v.z = fmaxf(o1v.z, 0.f); o1v.w = fmaxf(o1v.w, 0.f);
        ((float4*)x_out)[(size_t)d * 32 + 2 * l16]     = o0v;
        ((float4*)x_out)[(size_t)d * 32 + 2 * l16 + 1] = o1v;
    }
}

// ---------------------------------------------------------------------------
// MLP head via MFMA: 7 col-tiles (hidden 0..111, >=100 zero-padded in pack).
__global__ __launch_bounds__(256, 2) void mlp_kernel(
    const float* __restrict__ X, const unsigned* __restrict__ W1q,
    const float* __restrict__ b1, const float* __restrict__ W2,
    const float* __restrict__ b2, float* __restrict__ out, int n) {
    int tid = threadIdx.x;
    int lane = tid & 63;
    int wv = tid >> 6;
    int q = lane >> 4, nl = lane & 15;
    int row_blk = blockIdx.x * 64;
    int wrow = wv * 16;

    int arow = row_blk + wrow + nl;
    if (arow >= n) arow = n - 1;
    const float4* Xr = (const float4*)(X + (size_t)arow * HCONC);

    f32x4 acc[7];
#pragma unroll
    for (int t = 0; t < 7; t++) acc[t] = (f32x4){0.f, 0.f, 0.f, 0.f};

    const uint4* Wp4 = (const uint4*)W1q;
#pragma unroll
    for (int kb = 0; kb < 4; kb++) {
        float4 xa = Xr[kb * 8 + q * 2];
        float4 xb = Xr[kb * 8 + q * 2 + 1];
        uint4 ua;
        ua.x = pack_bf2(xa.x, xa.y);
        ua.y = pack_bf2(xa.z, xa.w);
        ua.z = pack_bf2(xb.x, xb.y);
        ua.w = pack_bf2(xb.z, xb.w);
        bf16x8 af = __builtin_bit_cast(bf16x8, ua);
#pragma unroll
        for (int t = 0; t < 7; t++) {
            uint4 ub = Wp4[(t * 4 + kb) * 64 + lane];
            bf16x8 bf = __builtin_bit_cast(bf16x8, ub);
            acc[t] = __builtin_amdgcn_mfma_f32_16x16x32_bf16(af, bf, acc[t], 0, 0, 0);
        }
    }

    float b1c[7], w2c[7];
#pragma unroll
    for (int t = 0; t < 7; t++) {
        int c = 16 * t + nl;
        bool vld = c < 100;
        b1c[t] = vld ? b1[c] : 0.f;
        w2c[t] = vld ? W2[c] : 0.f;
    }
    float b2v = b2[0];

#pragma unroll
    for (int reg = 0; reg < 4; reg++) {
        float sum = 0.f;
#pragma unroll
        for (int t = 0; t < 7; t++) {
            float hv = fmaxf(acc[t][reg] + b1c[t], 0.f);
            sum = fmaf(hv, w2c[t], sum);
        }
#pragma unroll
        for (int off = 1; off <= 8; off <<= 1)
            sum += __shfl_xor(sum, off);
        int row = row_blk + wrow + q * 4 + reg;
        if (nl == 0 && row < n)
            out[row] = 1.f / (1.f + __expf(-(sum + b2v)));
    }
}

// ---------------------------------------------------------------------------
extern "C" void kernel_launch(void* const* d_in, const int* in_sizes, int n_in,
                              void* d_out, int out_size, void* d_ws, size_t ws_size,
                              hipStream_t stream) {
    const float* x       = (const float*)d_in[0];
    const int*   ei      = (const int*)d_in[1];     // [2,E]: src then dst
    const int*   etype   = (const int*)d_in[2];
    const float* emb     = (const float*)d_in[3];   // [16,8]
    const float* W_l0    = (const float*)d_in[4];   // [32,128]
    const float* W_l1    = (const float*)d_in[5];   // [128,128]
    const float* W_l2    = (const float*)d_in[6];   // [128,128]
    const float* att_src = (const float*)d_in[7];   // [3,4,32]
    const float* att_dst = (const float*)d_in[8];
    const float* att_edge= (const float*)d_in[9];
    const float* W_edge  = (const float*)d_in[10];  // [3,8,128]
    const float* bias    = (const float*)d_in[11];  // [3,128]
    const float* mW1     = (const float*)d_in[12];  // [128,100]
    const float* mb1     = (const float*)d_in[13];
    const float* mW2     = (const float*)d_in[14];  // [100,1]
    const float* mb2     = (const float*)d_in[15];

    int n = in_sizes[0];   // 50000
    int E = in_sizes[2];   // 800000
    int nbuk = (n + 255) >> 8;   // 196

    // workspace carve (keep 16-byte alignment for uint4 views)
    float* p   = (float*)d_ws;
    float* xa  = p; p += (size_t)n * HCONC;
    float* xb  = p; p += (size_t)n * HCONC;
    float* ssrc = p; p += (size_t)n * NHEAD;
    float* sdst = p; p += (size_t)n * NHEAD;
    float* hbf  = p; p += (size_t)n * 32;          // fp8 h buffer (n*128 bytes)
    unsigned* Wl1q = (unsigned*)p; p += 8192;      // MFMA-B-packed W_l1
    unsigned* Wl2q = (unsigned*)p; p += 8192;      // MFMA-B-packed W_l2
    unsigned* W1q  = (unsigned*)p; p += 7168;      // MFMA-B-packed mW1 (7 tiles)
    int* row_ptr     = (int*)p;
    int* gcursor     = row_ptr + n + 1;
    int* cnt         = gcursor + 256;
    float* W0s    = (float*)(cnt + 16);
    float* SA0    = W0s + HCONC;
    float* SD0    = SA0 + NHEAD;
    float* meanat = SD0 + NHEAD;
    float* stab   = meanat + EDIM;   // 3*68 = 204, round to 256
    char* raw = (char*)(stab + 256);
    uint2* ebuf = (uint2*)(((uintptr_t)raw + 15) & ~(uintptr_t)15);  // nbuk*BCAP
    unsigned* col = (unsigned*)(ebuf + (size_t)nbuk * BCAP);         // E entries

    // CSR build: initpack -> tile counting-sort (binA) -> fine sort + setup (binB)
    initpack_kernel<<<93, 256, 0, stream>>>(W_l1, W_l2, mW1, Wl1q, Wl2q, W1q,
                                            gcursor, cnt, nbuk);
    binA_kernel<<<(E + TILE - 1) / TILE, 256, 0, stream>>>(ei, etype, E, nbuk,
                                                           gcursor, cnt, ebuf);
    binB_kernel<<<nbuk + 1, 256, 0, stream>>>(ebuf, gcursor, n, nbuk, row_ptr, col,
                                              W_l0, emb, cnt, att_src, att_dst,
                                              att_edge, W_edge, W0s, SA0, SD0,
                                              meanat, stab, E);

    // layer 0: fully-fused rank-1 aggregation (no h materialization)
    agg0_kernel<<<(n * 4 + 255) / 256, 256, 0, stream>>>(x, row_ptr, col, W0s, SA0, SD0,
                                                         stab + 0, bias + 0, xa, n);
    // layer 1
    transform_kernel<<<(n + 63) / 64, 256, 0, stream>>>(xa, Wl1q, att_src + 128, att_dst + 128,
                                                        (unsigned short*)hbf, ssrc, sdst, n);
    agg_kernel<<<(n + 3) / 4, 256, 0, stream>>>((const unsigned char*)hbf, ssrc, sdst, row_ptr, col,
                                                stab + 68, bias + 128, xa, xb, n);
    // layer 2
    transform_kernel<<<(n + 63) / 64, 256, 0, stream>>>(xb, Wl2q, att_src + 256, att_dst + 256,
                                                        (unsigned short*)hbf, ssrc, sdst, n);
    agg_kernel<<<(n + 3) / 4, 256, 0, stream>>>((const unsigned char*)hbf, ssrc, sdst, row_ptr, col,
                                                stab + 136, bias + 256, xb, xa, n);
    // MLP head (MFMA)
    mlp_kernel<<<(n + 63) / 64, 256, 0, stream>>>(xa, W1q, mb1, mW2, mb2, (float*)d_out, n);
}